// Round 17
// baseline (159.368 us; speedup 1.0000x reference)
//
#include <hip/hip_runtime.h>

#define SEQ 1024
#define NH  12
#define HD  64
#define HID 768
#define NB  4

#define LOG2E  1.4426950408889634f
#define SC2    0.18033688011112042f   // 0.125 * log2(e)
#define DTHR   11.541560327111707f    // 8 nats in log2 domain

typedef short bf16x8 __attribute__((ext_vector_type(8)));
typedef float f32x16 __attribute__((ext_vector_type(16)));

// LDS-only barrier: do NOT drain vmcnt (prefetched global loads stay in
// flight across the barrier).
#define LBAR() do {                                             \
    __builtin_amdgcn_sched_barrier(0);                          \
    asm volatile("s_waitcnt lgkmcnt(0)" ::: "memory");          \
    __builtin_amdgcn_s_barrier();                               \
    __builtin_amdgcn_sched_barrier(0);                          \
} while (0)

__device__ __forceinline__ unsigned short f2b(float f) {
    union { float f; unsigned u; } v; v.f = f;
    unsigned r = (v.u + 0x7FFFu + ((v.u >> 16) & 1u)) >> 16;
    return (unsigned short)r;
}
__device__ __forceinline__ float b2f(unsigned short s) {
    union { unsigned u; float f; } v; v.u = (unsigned)s << 16;
    return v.f;
}
__device__ __forceinline__ float g4(const float4& v, int e) {
    return e == 0 ? v.x : e == 1 ? v.y : e == 2 ? v.z : v.w;
}
__device__ __forceinline__ unsigned short u16g(const ushort4& v, int e) {
    return e == 0 ? v.x : e == 1 ? v.y : e == 2 ? v.z : v.w;
}
// packed f32 pair -> [hi:lo] bf16x2 in one VALU op (T12 primitive; no builtin)
__device__ __forceinline__ unsigned cvtpk(float lo, float hi) {
    unsigned w;
    asm("v_cvt_pk_bf16_f32 %0, %1, %2" : "=v"(w) : "v"(lo), "v"(hi));
    return w;
}

// C/D layout for v_mfma_f32_32x32x16_bf16: col = lane&31, row = ROWFN(reg, lane>>5)
#define ROWFN(r, h) (((r) & 3) + 8 * ((r) >> 2) + 4 * (h))

// ------------------------------------------------------------------
// fp32 -> bf16 conversion for X and E in ONE launch (grid-stride)
// ------------------------------------------------------------------
#define NX4 786432   // 4096*768/4
#define NE4 32752    // 2047*64/4

__global__ void cvt_all(const float* __restrict__ X, const float* __restrict__ E,
                        unsigned short* __restrict__ Xb, unsigned short* __restrict__ Eb) {
    int i = blockIdx.x * blockDim.x + threadIdx.x;
    const int stride = gridDim.x * blockDim.x;
    for (; i < NX4 + NE4; i += stride) {
        float4 v;
        if (i < NX4) v = ((const float4*)X)[i];
        else         v = ((const float4*)E)[i - NX4];
        uint2 o;
        o.x = cvtpk(v.x, v.y);
        o.y = cvtpk(v.z, v.w);
        if (i < NX4) ((uint2*)Xb)[i] = o;
        else         ((uint2*)Eb)[i - NX4] = o;
    }
}

// ------------------------------------------------------------------
// W [768][768] fp32 -> Wt [768 n][768 k] bf16 (transposed), 64x64 tiles
// ------------------------------------------------------------------
__global__ __launch_bounds__(256) void cvt_wt(
    const float* __restrict__ Wq, const float* __restrict__ Wk, const float* __restrict__ Wv,
    unsigned short* __restrict__ Wt)
{
    __shared__ float T[64][65];
    const int z = blockIdx.z;
    const float* __restrict__ W = (z == 0) ? Wq : (z == 1) ? Wk : Wv;
    const int k0 = blockIdx.x * 64, n0 = blockIdx.y * 64;
    const int tid = threadIdx.x;
    #pragma unroll
    for (int ir = 0; ir < 4; ++ir) {
        int r = ir * 16 + (tid >> 4);
        int c4 = (tid & 15) * 4;
        *(float4*)&T[r][c4] = *(const float4*)&W[(size_t)(k0 + r) * HID + n0 + c4];
    }
    __syncthreads();
    const int cc = tid >> 2, q = tid & 3;
    unsigned short* dst = Wt + (size_t)z * HID * HID + (size_t)(n0 + cc) * HID + k0 + q * 16;
    #pragma unroll
    for (int j4 = 0; j4 < 4; ++j4) {
        uint2 o;
        o.x = cvtpk(T[q * 16 + j4 * 4 + 0][cc], T[q * 16 + j4 * 4 + 1][cc]);
        o.y = cvtpk(T[q * 16 + j4 * 4 + 2][cc], T[q * 16 + j4 * 4 + 3][cc]);
        *(uint2*)(dst + j4 * 4) = o;
    }
}

// ------------------------------------------------------------------
// QKV GEMM (bf16 MFMA). z=0,1: out[z] = X@W+b in [bh][s][d] layout.
// z=2: operands SWAPPED -> computes V^T directly, out [bh][d][s] coalesced.
// Epilogue uses cvt_pk (1 VALU per pair vs 8).
// ------------------------------------------------------------------
__global__ __launch_bounds__(256) void gemm_qkv(
    const unsigned short* __restrict__ Xb,
    const unsigned short* __restrict__ Wt,
    const float* __restrict__ bq, const float* __restrict__ bk, const float* __restrict__ bv,
    unsigned short* __restrict__ qkv)
{
    __shared__ unsigned short Xs[128][64];
    __shared__ unsigned short Ws[128][64];

    const int tid = threadIdx.x;
    const int lane = tid & 63;
    const int wid = tid >> 6;
    const int c = lane & 31;
    const int h2 = lane >> 5;
    const int m0 = blockIdx.x * 128, N0 = blockIdx.y * 128, z = blockIdx.z;
    const unsigned short* __restrict__ Wz = Wt + (size_t)z * HID * HID;
    const float* __restrict__ bias = (z == 0) ? bq : (z == 1) ? bk : bv;

    f32x16 acc[2][2];
    #pragma unroll
    for (int i = 0; i < 2; ++i)
        #pragma unroll
        for (int j = 0; j < 2; ++j)
            #pragma unroll
            for (int r = 0; r < 16; ++r) acc[i][j][r] = 0.f;

    for (int k0 = 0; k0 < HID; k0 += 64) {
        __syncthreads();
        #pragma unroll
        for (int it = 0; it < 4; ++it) {
            int t16 = tid + 256 * it;
            int row = t16 >> 3, s = t16 & 7;
            bf16x8 xv = *(const bf16x8*)(Xb + (size_t)(m0 + row) * HID + k0 + s * 8);
            *(bf16x8*)&Xs[row][(s ^ (row & 7)) * 8] = xv;
            bf16x8 wv = *(const bf16x8*)(Wz + (size_t)(N0 + row) * HID + k0 + s * 8);
            *(bf16x8*)&Ws[row][(s ^ (row & 7)) * 8] = wv;
        }
        __syncthreads();
        #pragma unroll
        for (int kc = 0; kc < 4; ++kc) {
            const int slot = kc * 2 + h2;
            bf16x8 af[2], bf_[2];
            #pragma unroll
            for (int i = 0; i < 2; ++i) {
                int ar = 64 * (wid >> 1) + 32 * i + c;
                int br = 64 * (wid & 1) + 32 * i + c;
                if (z != 2) {
                    af[i]  = *(const bf16x8*)&Xs[ar][(slot ^ (ar & 7)) * 8];
                    bf_[i] = *(const bf16x8*)&Ws[br][(slot ^ (br & 7)) * 8];
                } else {
                    af[i]  = *(const bf16x8*)&Ws[ar][(slot ^ (ar & 7)) * 8];
                    bf_[i] = *(const bf16x8*)&Xs[br][(slot ^ (br & 7)) * 8];
                }
            }
            #pragma unroll
            for (int i = 0; i < 2; ++i)
                #pragma unroll
                for (int j = 0; j < 2; ++j)
                    acc[i][j] = __builtin_amdgcn_mfma_f32_32x32x16_bf16(af[i], bf_[j], acc[i][j], 0, 0, 0);
        }
    }

    unsigned short* outz = qkv + (size_t)z * (NB * SEQ * HID);
    if (z != 2) {
        #pragma unroll
        for (int j = 0; j < 2; ++j) {
            const int n = N0 + 64 * (wid & 1) + 32 * j + c;
            const float bv_ = bias[n];
            const int hh = n >> 6, d = n & 63;
            #pragma unroll
            for (int i = 0; i < 2; ++i) {
                #pragma unroll
                for (int r8 = 0; r8 < 8; ++r8) {
                    // pair (2r8, 2r8+1): ROWFN(2r8+1)=ROWFN(2r8)+1 (even r)
                    const unsigned w = cvtpk(acc[i][j][2 * r8] + bv_, acc[i][j][2 * r8 + 1] + bv_);
                    int m = m0 + 64 * (wid >> 1) + 32 * i + ROWFN(2 * r8, h2);
                    int bb = m >> 10, ss = m & 1023;
                    unsigned short* p = &outz[(((size_t)bb * NH + hh) * SEQ + ss) * HD + d];
                    p[0]  = (unsigned short)w;
                    p[HD] = (unsigned short)(w >> 16);   // ss+1 -> +HD elements
                }
            }
        }
    } else {
        #pragma unroll
        for (int i = 0; i < 2; ++i) {
            #pragma unroll
            for (int r8 = 0; r8 < 8; ++r8) {
                int n = N0 + 64 * (wid >> 1) + 32 * i + ROWFN(2 * r8, h2);
                int hh = n >> 6, d = n & 63;   // d <= 30 within 32-block -> d+1 no wrap
                float b0 = bias[n], b1 = bias[n + 1];
                #pragma unroll
                for (int j = 0; j < 2; ++j) {
                    const unsigned w = cvtpk(acc[i][j][2 * r8] + b0, acc[i][j][2 * r8 + 1] + b1);
                    int m = m0 + 64 * (wid & 1) + 32 * j + c;
                    int bb = m >> 10, ss = m & 1023;
                    unsigned short* p = &outz[(((size_t)bb * NH + hh) * HD + d) * SEQ + ss];
                    p[0]   = (unsigned short)w;
                    p[SEQ] = (unsigned short)(w >> 16);  // d+1 -> +SEQ elements
                }
            }
        }
    }
}

// ------------------------------------------------------------------
// Fused attention: r11 dataflow (register-prefetch K/E, no Ks/Es LDS)
// + r16 cvt_pk VALU diet. LDS = 53.8 KB -> 3 blocks/CU; the 768-block
// grid is exactly one resident pass (256 CUs x 3).
// ------------------------------------------------------------------
__global__ __launch_bounds__(256, 2) void attn_mfma(
    const unsigned short* __restrict__ Qg,   // [bh][s][d] bf16
    const unsigned short* __restrict__ Kg,   // [bh][s][d] bf16
    const unsigned short* __restrict__ Vtg,  // [bh][d][s] bf16 (pre-transposed)
    const unsigned short* __restrict__ Eg,   // [2047][64] bf16
    const float* __restrict__ mask,          // [4][1024]
    float* __restrict__ out)                 // [4][1024][768] fp32
{
    __shared__ unsigned short Vt[64][64];    // [d][r], swizzled 16B slots (single buf)
    __shared__ float S1[64][68];             // row-major QK^T
    __shared__ unsigned short MSS[64][76];   // MSS[l][r] = M[l][l-r+63]
    __shared__ unsigned short NST[64][76];   // NST[l][r] = N[r][l-r+63]
    __shared__ unsigned short Pl[64][64];    // P bf16, swizzled slots
    __shared__ float Corr[64];
    __shared__ float InvL[64];
    __shared__ int Fl[2];

    const int tid = threadIdx.x;
    const int lane = tid & 63;
    const int wid = tid >> 6;
    const int c = lane & 31;
    const int h2 = lane >> 5;
    const int RB = 32 * (wid >> 1);
    const int CB = 32 * (wid & 1);
    const int j0 = 64 * (wid & 1) + c;       // M/N fragment column (frag0)

    const int l0 = blockIdx.x * 64;
    const int bh = blockIdx.y;
    const int b = bh / NH;
    const int hh = bh - b * NH;

    const unsigned short* __restrict__ Qb = Qg + (size_t)bh * SEQ * HD;
    const unsigned short* __restrict__ Kb = Kg + (size_t)bh * SEQ * HD;
    const unsigned short* __restrict__ Vb = Vtg + (size_t)bh * HD * SEQ;
    const float* __restrict__ mrow_base = mask + (size_t)b * SEQ;

    if (tid < 2) Fl[tid] = 0;

    // persistent Q A-fragments
    bf16x8 qa[4];
    #pragma unroll
    for (int kc = 0; kc < 4; ++kc)
        qa[kc] = *(const bf16x8*)(Qb + (size_t)(l0 + RB + c) * HD + kc * 16 + h2 * 8);

    f32x16 Oa;
    #pragma unroll
    for (int r = 0; r < 16; ++r) Oa[r] = 0.f;

    const int li = tid >> 2;
    const int c0q = (tid & 3) * 16;
    const int kli = (li ^ (li >> 3)) & 7;
    const int vd0 = tid >> 3, vs8 = tid & 7;
    const int kd0 = (vd0 ^ (vd0 >> 3)) & 7;
    const int kd1 = ((vd0 + 32) ^ ((vd0 + 32) >> 3)) & 7;
    float m_run = -1e30f, lsum = 0.f;

    // ---- full prologue prefetch (tile 0) ----
    bf16x8 kb[4], ka[4], e0[4], e1[4], vc0, vc1;
    {
        const int jr0 = l0 + 960 + j0;
        const int jra = jr0 > 2046 ? 2046 : jr0;
        const int jr1x = jr0 + 32;
        const int jrb = jr1x > 2046 ? 2046 : jr1x;
        #pragma unroll
        for (int kc = 0; kc < 4; ++kc) {
            kb[kc] = *(const bf16x8*)(Kb + (size_t)(CB + c) * HD + kc * 16 + h2 * 8);
            ka[kc] = *(const bf16x8*)(Kb + (size_t)(RB + c) * HD + kc * 16 + h2 * 8);
            e0[kc] = *(const bf16x8*)(Eg + (size_t)jra * HD + kc * 16 + h2 * 8);
            e1[kc] = *(const bf16x8*)(Eg + (size_t)jrb * HD + kc * 16 + h2 * 8);
        }
        vc0 = *(const bf16x8*)(Vb + (size_t)vd0 * SEQ + vs8 * 8);
        vc1 = *(const bf16x8*)(Vb + (size_t)(vd0 + 32) * SEQ + vs8 * 8);
    }

    for (int r0 = 0; r0 < SEQ; r0 += 64) {
        const int buf = (r0 >> 6) & 1;
        int r0n = r0 + 64; if (r0n >= SEQ) r0n = 0;

        // ---- loop top: mask(t) + V(t+1) loads ----
        float4 mk[4];
        #pragma unroll
        for (int q = 0; q < 4; ++q)
            mk[q] = *(const float4*)(mrow_base + r0 + c0q + 4 * q);
        bf16x8 vn0 = *(const bf16x8*)(Vb + (size_t)vd0 * SEQ + r0n + vs8 * 8);
        bf16x8 vn1 = *(const bf16x8*)(Vb + (size_t)(vd0 + 32) * SEQ + r0n + vs8 * 8);

        // ---- cluster 1: S1 (consumes kb) ----
        {
            f32x16 s1a;
            #pragma unroll
            for (int r = 0; r < 16; ++r) s1a[r] = 0.f;
            __builtin_amdgcn_s_setprio(1);
            #pragma unroll
            for (int kc = 0; kc < 4; ++kc)
                s1a = __builtin_amdgcn_mfma_f32_32x32x16_bf16(qa[kc], kb[kc], s1a, 0, 0, 0);
            __builtin_amdgcn_s_setprio(0);
            #pragma unroll
            for (int rq = 0; rq < 16; ++rq)
                S1[RB + ROWFN(rq, h2)][CB + c] = s1a[rq];
        }
        // kb free -> prefetch next tile's K-B frags
        #pragma unroll
        for (int kc = 0; kc < 4; ++kc)
            kb[kc] = *(const bf16x8*)(Kb + (size_t)(r0n + CB + c) * HD + kc * 16 + h2 * 8);
        __builtin_amdgcn_sched_barrier(0);

        // ---- cluster 2: M0/N0 (consumes e0); wave2 skips ma0, wave0 skips na0 ----
        {
            f32x16 ma0, na0;
            #pragma unroll
            for (int r = 0; r < 16; ++r) { ma0[r] = 0.f; na0[r] = 0.f; }
            __builtin_amdgcn_s_setprio(1);
            if (wid != 2) {
                #pragma unroll
                for (int kc = 0; kc < 4; ++kc)
                    ma0 = __builtin_amdgcn_mfma_f32_32x32x16_bf16(qa[kc], e0[kc], ma0, 0, 0, 0);
            }
            if (wid != 0) {
                #pragma unroll
                for (int kc = 0; kc < 4; ++kc)
                    na0 = __builtin_amdgcn_mfma_f32_32x32x16_bf16(ka[kc], e0[kc], na0, 0, 0, 0);
            }
            __builtin_amdgcn_s_setprio(0);
            if (wid != 2) {
                #pragma unroll
                for (int q8 = 0; q8 < 8; ++q8) {
                    const unsigned w = cvtpk(ma0[2 * q8], ma0[2 * q8 + 1]);
                    const int lr = RB + ROWFN(2 * q8, h2);   // ROWFN(2q+1)=ROWFN(2q)+1
                    const int rA = lr - j0 + 63;
                    if ((unsigned)rA < 64u) MSS[lr][rA] = (unsigned short)w;
                    if ((unsigned)(rA + 1) < 64u) MSS[lr + 1][rA + 1] = (unsigned short)(w >> 16);
                }
            }
            if (wid != 0) {
                #pragma unroll
                for (int q8 = 0; q8 < 8; ++q8) {
                    const unsigned w = cvtpk(na0[2 * q8], na0[2 * q8 + 1]);
                    const int lr = RB + ROWFN(2 * q8, h2);
                    const int lA = j0 + lr - 63;
                    if ((unsigned)lA < 64u) NST[lA][lr] = (unsigned short)w;
                    if ((unsigned)(lA + 1) < 64u) NST[lA + 1][lr + 1] = (unsigned short)(w >> 16);
                }
            }
        }
        __builtin_amdgcn_sched_barrier(0);

        // ---- cluster 3: M1/N1 (consumes e1, last use of ka); wave1 skips ma1, wave3 skips na1 ----
        {
            f32x16 ma1, na1;
            #pragma unroll
            for (int r = 0; r < 16; ++r) { ma1[r] = 0.f; na1[r] = 0.f; }
            __builtin_amdgcn_s_setprio(1);
            if (wid != 1) {
                #pragma unroll
                for (int kc = 0; kc < 4; ++kc)
                    ma1 = __builtin_amdgcn_mfma_f32_32x32x16_bf16(qa[kc], e1[kc], ma1, 0, 0, 0);
            }
            if (wid != 3) {
                #pragma unroll
                for (int kc = 0; kc < 4; ++kc)
                    na1 = __builtin_amdgcn_mfma_f32_32x32x16_bf16(ka[kc], e1[kc], na1, 0, 0, 0);
            }
            __builtin_amdgcn_s_setprio(0);
            if (wid != 1) {
                #pragma unroll
                for (int q8 = 0; q8 < 8; ++q8) {
                    const unsigned w = cvtpk(ma1[2 * q8], ma1[2 * q8 + 1]);
                    const int lr = RB + ROWFN(2 * q8, h2);
                    const int rB = lr - j0 + 31;
                    if ((unsigned)rB < 64u) MSS[lr][rB] = (unsigned short)w;
                    if ((unsigned)(rB + 1) < 64u) MSS[lr + 1][rB + 1] = (unsigned short)(w >> 16);
                }
            }
            if (wid != 3) {
                #pragma unroll
                for (int q8 = 0; q8 < 8; ++q8) {
                    const unsigned w = cvtpk(na1[2 * q8], na1[2 * q8 + 1]);
                    const int lr = RB + ROWFN(2 * q8, h2);
                    const int lB = j0 + lr - 31;
                    if ((unsigned)lB < 64u) NST[lB][lr] = (unsigned short)w;
                    if ((unsigned)(lB + 1) < 64u) NST[lB + 1][lr + 1] = (unsigned short)(w >> 16);
                }
            }
        }
        __builtin_amdgcn_sched_barrier(0);

        // ---- prefetch next tile's ka/e0/e1 (stays in flight across LBAR) ----
        {
            const int jr0n = l0 - r0n + 960 + j0;
            const int jran = jr0n > 2046 ? 2046 : jr0n;
            const int jr1n = jr0n + 32;
            const int jrbn = jr1n > 2046 ? 2046 : jr1n;
            #pragma unroll
            for (int kc = 0; kc < 4; ++kc) {
                ka[kc] = *(const bf16x8*)(Kb + (size_t)(r0n + RB + c) * HD + kc * 16 + h2 * 8);
                e0[kc] = *(const bf16x8*)(Eg + (size_t)jran * HD + kc * 16 + h2 * 8);
                e1[kc] = *(const bf16x8*)(Eg + (size_t)jrbn * HD + kc * 16 + h2 * 8);
            }
        }

        LBAR();            // BARRIER-A: S1/MSS/NST visible (LDS only, no vmcnt drain)

        // ---- stage Vt (single buffer; safe after barrier-A) ----
        *(bf16x8*)&Vt[vd0][(vs8 ^ kd0) * 8] = vc0;
        *(bf16x8*)&Vt[vd0 + 32][(vs8 ^ kd1) * 8] = vc1;

        // ---- softmax: thread owns row li, cols c0q..c0q+15 (all-vector reads) ----
        float4 s4[4]; ushort4 mm[4], nn[4];
        #pragma unroll
        for (int q = 0; q < 4; ++q) {
            s4[q] = *(const float4*)&S1[li][c0q + 4 * q];
            mm[q] = *(const ushort4*)&MSS[li][c0q + 4 * q];
            nn[q] = *(const ushort4*)&NST[li][c0q + 4 * q];
        }
        float sc[16];
        #pragma unroll
        for (int j = 0; j < 16; ++j) {
            float mv = b2f(u16g(mm[j >> 2], j & 3));
            float nv = b2f(u16g(nn[j >> 2], j & 3));
            sc[j] = (g4(s4[j >> 2], j & 3) + mv + nv) * SC2 + g4(mk[j >> 2], j & 3) * LOG2E;
        }
        float tmax = sc[0];
        #pragma unroll
        for (int j = 1; j < 16; ++j) tmax = fmaxf(tmax, sc[j]);
        tmax = fmaxf(tmax, __shfl_xor(tmax, 1));
        tmax = fmaxf(tmax, __shfl_xor(tmax, 2));
        const bool upd = tmax > m_run + DTHR;          // defer-max (T13)
        const float m_new = upd ? tmax : m_run;
        const float corr = upd ? __builtin_amdgcn_exp2f(m_run - m_new) : 1.0f;
        if (upd) Fl[buf] = 1;                          // benign same-value race
        float tsum = 0.f;
        unsigned pw[8];
        #pragma unroll
        for (int j = 0; j < 8; ++j) {
            float p0 = __builtin_amdgcn_exp2f(sc[2 * j] - m_new);
            float p1 = __builtin_amdgcn_exp2f(sc[2 * j + 1] - m_new);
            tsum += p0;
            tsum += p1;
            pw[j] = cvtpk(p0, p1);                     // [p1:p0] = bf16x8 word order
        }
        tsum += __shfl_xor(tsum, 1);
        tsum += __shfl_xor(tsum, 2);
        lsum = lsum * corr + tsum;
        m_run = m_new;
        if ((tid & 3) == 0) Corr[li] = corr;
        #pragma unroll
        for (int sblk = 0; sblk < 2; ++sblk) {
            union { unsigned u[4]; bf16x8 v; } pk;
            pk.u[0] = pw[sblk * 4 + 0];
            pk.u[1] = pw[sblk * 4 + 1];
            pk.u[2] = pw[sblk * 4 + 2];
            pk.u[3] = pw[sblk * 4 + 3];
            const int slot = ((c0q >> 3) + sblk) ^ kli;
            *(bf16x8*)&Pl[li][slot * 8] = pk.v;
        }

        LBAR();            // BARRIER-B: Pl/Corr/Fl + Vt writes visible

        // ---- PV ----
        if (Fl[buf]) {
            #pragma unroll
            for (int q = 0; q < 4; ++q) {
                float4 cr = *(const float4*)&Corr[RB + 8 * q + 4 * h2];
                Oa[4 * q + 0] *= cr.x; Oa[4 * q + 1] *= cr.y;
                Oa[4 * q + 2] *= cr.z; Oa[4 * q + 3] *= cr.w;
            }
        }
        if (tid == 0) Fl[buf ^ 1] = 0;
        const int lrow = RB + c;
        const int drow = CB + c;
        const int klr = (lrow ^ (lrow >> 3)) & 7;
        const int kdr = (drow ^ (drow >> 3)) & 7;
        __builtin_amdgcn_s_setprio(1);
        #pragma unroll
        for (int kc = 0; kc < 4; ++kc) {
            const int slot = kc * 2 + h2;
            bf16x8 pa  = *(const bf16x8*)&Pl[lrow][(slot ^ klr) * 8];
            bf16x8 vbf = *(const bf16x8*)&Vt[drow][(slot ^ kdr) * 8];
            Oa = __builtin_amdgcn_mfma_f32_32x32x16_bf16(pa, vbf, Oa, 0, 0, 0);
        }
        __builtin_amdgcn_s_setprio(0);

        vc0 = vn0; vc1 = vn1;
    }

    if ((tid & 3) == 0) InvL[li] = 1.0f / lsum;
    __syncthreads();
    #pragma unroll
    for (int q = 0; q < 4; ++q) {
        float4 iv = *(const float4*)&InvL[RB + 8 * q + 4 * h2];
        #pragma unroll
        for (int e = 0; e < 4; ++e) {
            const int l = RB + 8 * q + 4 * h2 + e;
            out[((size_t)b * SEQ + l0 + l) * HID + hh * HD + CB + c] = Oa[4 * q + e] * g4(iv, e);
        }
    }
}

// ------------------------------------------------------------------
extern "C" void kernel_launch(void* const* d_in, const int* in_sizes, int n_in,
                              void* d_out, int out_size, void* d_ws, size_t ws_size,
                              hipStream_t stream) {
    const float* hidden = (const float*)d_in[0];
    const float* mask   = (const float*)d_in[1];
    const float* Wq     = (const float*)d_in[2];
    const float* bq     = (const float*)d_in[3];
    const float* Wk     = (const float*)d_in[4];
    const float* bk     = (const float*)d_in[5];
    const float* Wv     = (const float*)d_in[6];
    const float* bv     = (const float*)d_in[7];
    const float* E      = (const float*)d_in[8];
    float* outp = (float*)d_out;

    unsigned short* ws  = (unsigned short*)d_ws;
    unsigned short* Xbf = ws;                      // 4096*768            = 3145728
    unsigned short* Wt  = ws + 3145728;            // 3*768*768           = 1769472
    unsigned short* Ebf = ws + 4915200;            // 2047*64             = 131008
    unsigned short* qkv = ws + 5046272;            // 3*48*1024*64        = 9437184

    cvt_all<<<dim3(1024), 256, 0, stream>>>(hidden, E, Xbf, Ebf);
    cvt_wt<<<dim3(12, 12, 3), 256, 0, stream>>>(Wq, Wk, Wv, Wt);
    gemm_qkv<<<dim3(32, 6, 3), 256, 0, stream>>>(Xbf, Wt, bq, bk, bv, qkv);
    const size_t per = (size_t)NB * SEQ * HID;
    attn_mfma<<<dim3(16, 48), 256, 0, stream>>>(qkv, qkv + per, qkv + 2 * per,
                                                Ebf, mask, outp);
}

// Round 18
// 153.206 us; speedup vs baseline: 1.0402x; 1.0402x over previous
//
#include <hip/hip_runtime.h>

#define SEQ 1024
#define NH  12
#define HD  64
#define HID 768
#define NB  4

#define LOG2E  1.4426950408889634f
#define SC2    0.18033688011112042f   // 0.125 * log2(e)
#define DTHR   11.541560327111707f    // 8 nats in log2 domain

typedef short bf16x8 __attribute__((ext_vector_type(8)));
typedef float f32x16 __attribute__((ext_vector_type(16)));

// LDS-only barrier: do NOT drain vmcnt (prefetched global loads stay in
// flight across the barrier).
#define LBAR() do {                                             \
    __builtin_amdgcn_sched_barrier(0);                          \
    asm volatile("s_waitcnt lgkmcnt(0)" ::: "memory");          \
    __builtin_amdgcn_s_barrier();                               \
    __builtin_amdgcn_sched_barrier(0);                          \
} while (0)

__device__ __forceinline__ float b2f(unsigned short s) {
    union { unsigned u; float f; } v; v.u = (unsigned)s << 16;
    return v.f;
}
__device__ __forceinline__ float g4(const float4& v, int e) {
    return e == 0 ? v.x : e == 1 ? v.y : e == 2 ? v.z : v.w;
}
__device__ __forceinline__ unsigned short u16g(const ushort4& v, int e) {
    return e == 0 ? v.x : e == 1 ? v.y : e == 2 ? v.z : v.w;
}
// packed f32 pair -> [hi:lo] bf16x2 in one VALU op (T12 primitive; no builtin)
__device__ __forceinline__ unsigned cvtpk(float lo, float hi) {
    unsigned w;
    asm("v_cvt_pk_bf16_f32 %0, %1, %2" : "=v"(w) : "v"(lo), "v"(hi));
    return w;
}

// C/D layout for v_mfma_f32_32x32x16_bf16: col = lane&31, row = ROWFN(reg, lane>>5)
#define ROWFN(r, h) (((r) & 3) + 8 * ((r) >> 2) + 4 * (h))

// ------------------------------------------------------------------
// Fused prep, ONE launch, flat 1D grid:
//   blocks [0,432):    W[z] transpose+cvt, 64x64 tiles (12x12x3 flattened)
//   blocks [432,1456): grid-stride fp32->bf16 cvt of X and E (1024 blocks,
//                      same parallelism as the old cvt_all)
// ------------------------------------------------------------------
#define NX4 786432   // 4096*768/4
#define NE4 32752    // 2047*64/4
#define NWT 432      // 12*12*3 W-tiles
#define NCVT 1024

__global__ __launch_bounds__(256) void prep(
    const float* __restrict__ X, const float* __restrict__ E,
    const float* __restrict__ Wq, const float* __restrict__ Wk, const float* __restrict__ Wv,
    unsigned short* __restrict__ Xb, unsigned short* __restrict__ Eb,
    unsigned short* __restrict__ Wt)
{
    __shared__ float T[64][65];
    const int bid = blockIdx.x;
    const int tid = threadIdx.x;

    if (bid < NWT) {
        const int z = bid / 144;
        const int rem = bid - z * 144;
        const int k0 = (rem % 12) * 64, n0 = (rem / 12) * 64;
        const float* __restrict__ W = (z == 0) ? Wq : (z == 1) ? Wk : Wv;
        #pragma unroll
        for (int ir = 0; ir < 4; ++ir) {
            int r = ir * 16 + (tid >> 4);
            int c4 = (tid & 15) * 4;
            *(float4*)&T[r][c4] = *(const float4*)&W[(size_t)(k0 + r) * HID + n0 + c4];
        }
        __syncthreads();
        const int cc = tid >> 2, q = tid & 3;
        unsigned short* dst = Wt + (size_t)z * HID * HID + (size_t)(n0 + cc) * HID + k0 + q * 16;
        #pragma unroll
        for (int j4 = 0; j4 < 4; ++j4) {
            uint2 o;
            o.x = cvtpk(T[q * 16 + j4 * 4 + 0][cc], T[q * 16 + j4 * 4 + 1][cc]);
            o.y = cvtpk(T[q * 16 + j4 * 4 + 2][cc], T[q * 16 + j4 * 4 + 3][cc]);
            *(uint2*)(dst + j4 * 4) = o;
        }
    } else {
        int i = (bid - NWT) * 256 + tid;
        const int stride = NCVT * 256;
        for (; i < NX4 + NE4; i += stride) {
            float4 v;
            if (i < NX4) v = ((const float4*)X)[i];
            else         v = ((const float4*)E)[i - NX4];
            uint2 o;
            o.x = cvtpk(v.x, v.y);
            o.y = cvtpk(v.z, v.w);
            if (i < NX4) ((uint2*)Xb)[i] = o;
            else         ((uint2*)Eb)[i - NX4] = o;
        }
    }
}

// ------------------------------------------------------------------
// QKV GEMM (bf16 MFMA). z=0,1: out[z] = X@W+b in [bh][s][d] layout.
// z=2: operands SWAPPED -> computes V^T directly, out [bh][d][s] coalesced.
// Epilogue uses cvt_pk (1 VALU per pair vs 8).
// ------------------------------------------------------------------
__global__ __launch_bounds__(256) void gemm_qkv(
    const unsigned short* __restrict__ Xb,
    const unsigned short* __restrict__ Wt,
    const float* __restrict__ bq, const float* __restrict__ bk, const float* __restrict__ bv,
    unsigned short* __restrict__ qkv)
{
    __shared__ unsigned short Xs[128][64];
    __shared__ unsigned short Ws[128][64];

    const int tid = threadIdx.x;
    const int lane = tid & 63;
    const int wid = tid >> 6;
    const int c = lane & 31;
    const int h2 = lane >> 5;
    const int m0 = blockIdx.x * 128, N0 = blockIdx.y * 128, z = blockIdx.z;
    const unsigned short* __restrict__ Wz = Wt + (size_t)z * HID * HID;
    const float* __restrict__ bias = (z == 0) ? bq : (z == 1) ? bk : bv;

    f32x16 acc[2][2];
    #pragma unroll
    for (int i = 0; i < 2; ++i)
        #pragma unroll
        for (int j = 0; j < 2; ++j)
            #pragma unroll
            for (int r = 0; r < 16; ++r) acc[i][j][r] = 0.f;

    for (int k0 = 0; k0 < HID; k0 += 64) {
        __syncthreads();
        #pragma unroll
        for (int it = 0; it < 4; ++it) {
            int t16 = tid + 256 * it;
            int row = t16 >> 3, s = t16 & 7;
            bf16x8 xv = *(const bf16x8*)(Xb + (size_t)(m0 + row) * HID + k0 + s * 8);
            *(bf16x8*)&Xs[row][(s ^ (row & 7)) * 8] = xv;
            bf16x8 wv = *(const bf16x8*)(Wz + (size_t)(N0 + row) * HID + k0 + s * 8);
            *(bf16x8*)&Ws[row][(s ^ (row & 7)) * 8] = wv;
        }
        __syncthreads();
        #pragma unroll
        for (int kc = 0; kc < 4; ++kc) {
            const int slot = kc * 2 + h2;
            bf16x8 af[2], bf_[2];
            #pragma unroll
            for (int i = 0; i < 2; ++i) {
                int ar = 64 * (wid >> 1) + 32 * i + c;
                int br = 64 * (wid & 1) + 32 * i + c;
                if (z != 2) {
                    af[i]  = *(const bf16x8*)&Xs[ar][(slot ^ (ar & 7)) * 8];
                    bf_[i] = *(const bf16x8*)&Ws[br][(slot ^ (br & 7)) * 8];
                } else {
                    af[i]  = *(const bf16x8*)&Ws[ar][(slot ^ (ar & 7)) * 8];
                    bf_[i] = *(const bf16x8*)&Xs[br][(slot ^ (br & 7)) * 8];
                }
            }
            #pragma unroll
            for (int i = 0; i < 2; ++i)
                #pragma unroll
                for (int j = 0; j < 2; ++j)
                    acc[i][j] = __builtin_amdgcn_mfma_f32_32x32x16_bf16(af[i], bf_[j], acc[i][j], 0, 0, 0);
        }
    }

    unsigned short* outz = qkv + (size_t)z * (NB * SEQ * HID);
    if (z != 2) {
        #pragma unroll
        for (int j = 0; j < 2; ++j) {
            const int n = N0 + 64 * (wid & 1) + 32 * j + c;
            const float bv_ = bias[n];
            const int hh = n >> 6, d = n & 63;
            #pragma unroll
            for (int i = 0; i < 2; ++i) {
                #pragma unroll
                for (int r8 = 0; r8 < 8; ++r8) {
                    // pair (2r8, 2r8+1): ROWFN(2r8+1)=ROWFN(2r8)+1 (even r)
                    const unsigned w = cvtpk(acc[i][j][2 * r8] + bv_, acc[i][j][2 * r8 + 1] + bv_);
                    int m = m0 + 64 * (wid >> 1) + 32 * i + ROWFN(2 * r8, h2);
                    int bb = m >> 10, ss = m & 1023;
                    unsigned short* p = &outz[(((size_t)bb * NH + hh) * SEQ + ss) * HD + d];
                    p[0]  = (unsigned short)w;
                    p[HD] = (unsigned short)(w >> 16);   // ss+1 -> +HD elements
                }
            }
        }
    } else {
        #pragma unroll
        for (int i = 0; i < 2; ++i) {
            #pragma unroll
            for (int r8 = 0; r8 < 8; ++r8) {
                int n = N0 + 64 * (wid >> 1) + 32 * i + ROWFN(2 * r8, h2);
                int hh = n >> 6, d = n & 63;   // d <= 30 within 32-block -> d+1 no wrap
                float b0 = bias[n], b1 = bias[n + 1];
                #pragma unroll
                for (int j = 0; j < 2; ++j) {
                    const unsigned w = cvtpk(acc[i][j][2 * r8] + b0, acc[i][j][2 * r8 + 1] + b1);
                    int m = m0 + 64 * (wid & 1) + 32 * j + c;
                    int bb = m >> 10, ss = m & 1023;
                    unsigned short* p = &outz[(((size_t)bb * NH + hh) * HD + d) * SEQ + ss];
                    p[0]   = (unsigned short)w;
                    p[SEQ] = (unsigned short)(w >> 16);  // d+1 -> +SEQ elements
                }
            }
        }
    }
}

// ------------------------------------------------------------------
// Fused attention: r16 exact (best measured: 121.2 us).
// r13 K/E LDS staging + cvt_pk VALU diet; 2 LDS-only barriers/tile;
// register-staged coalesced loads one tile ahead.
// ------------------------------------------------------------------
__global__ __launch_bounds__(256, 2) void attn_mfma(
    const unsigned short* __restrict__ Qg,   // [bh][s][d] bf16
    const unsigned short* __restrict__ Kg,   // [bh][s][d] bf16
    const unsigned short* __restrict__ Vtg,  // [bh][d][s] bf16 (pre-transposed)
    const unsigned short* __restrict__ Eg,   // [2047][64] bf16
    const float* __restrict__ mask,          // [4][1024]
    float* __restrict__ out)                 // [4][1024][768] fp32
{
    __shared__ unsigned short Ks[64][64];    // K tile, 16B-slot swizzled
    __shared__ unsigned short Es[128][64];   // E window (jb..jb+127), swizzled
    __shared__ unsigned short Vt[64][64];    // V^T tile, swizzled
    __shared__ float S1[64][68];             // row-major QK^T
    __shared__ unsigned short MSS[64][76];   // MSS[l][r] = M[l][l-r+63]
    __shared__ unsigned short NST[64][76];   // NST[l][r] = N[r][l-r+63]
    __shared__ unsigned short Pl[64][64];    // P bf16, swizzled slots
    __shared__ float Corr[64];
    __shared__ float InvL[64];
    __shared__ int Fl[2];

    const int tid = threadIdx.x;
    const int lane = tid & 63;
    const int wid = tid >> 6;
    const int c = lane & 31;
    const int h2 = lane >> 5;
    const int RB = 32 * (wid >> 1);
    const int CB = 32 * (wid & 1);
    const int j0 = 64 * (wid & 1) + c;       // M/N fragment column (frag0), E local row

    const int l0 = blockIdx.x * 64;
    const int bh = blockIdx.y;
    const int b = bh / NH;
    const int hh = bh - b * NH;

    const unsigned short* __restrict__ Qb = Qg + (size_t)bh * SEQ * HD;
    const unsigned short* __restrict__ Kb = Kg + (size_t)bh * SEQ * HD;
    const unsigned short* __restrict__ Vb = Vtg + (size_t)bh * HD * SEQ;
    const float* __restrict__ mrow_base = mask + (size_t)b * SEQ;

    if (tid < 2) Fl[tid] = 0;

    // persistent Q A-fragments (once per block -> gather cost amortized)
    bf16x8 qa[4];
    #pragma unroll
    for (int kc = 0; kc < 4; ++kc)
        qa[kc] = *(const bf16x8*)(Qb + (size_t)(l0 + RB + c) * HD + kc * 16 + h2 * 8);

    f32x16 Oa;
    #pragma unroll
    for (int r = 0; r < 16; ++r) Oa[r] = 0.f;

    const int li = tid >> 2;
    const int c0q = (tid & 3) * 16;
    const int kli = (li ^ (li >> 3)) & 7;
    const int vd0 = tid >> 3, vs8 = tid & 7;
    const int kd0 = (vd0 ^ (vd0 >> 3)) & 7;
    const int kd1 = ((vd0 + 32) ^ ((vd0 + 32) >> 3)) & 7;

    // staging thread map: row = srow (+32*it), slot = su; swizzled source col
    const int srow = tid >> 3, su = tid & 7;
    const int sswz = (su ^ (srow & 7)) * 8;  // element offset within row

    // fragment-read swizzle key (CB/RB/64-offsets are 0 mod 8)
    const int swk = c & 7;

    float m_run = -1e30f, lsum = 0.f;

    // ---- prologue: stage tile 0 K/E; prefetch V(0) ----
    bf16x8 kst0, kst1, est[4], vc0, vc1;
    {
        const int jb0 = l0 + 960;
        kst0 = *(const bf16x8*)(Kb + (size_t)srow * HD + sswz);
        kst1 = *(const bf16x8*)(Kb + (size_t)(srow + 32) * HD + sswz);
        #pragma unroll
        for (int it = 0; it < 4; ++it)
            est[it] = *(const bf16x8*)(Eg + (size_t)(jb0 + srow + 32 * it) * HD + sswz);
        vc0 = *(const bf16x8*)(Vb + (size_t)vd0 * SEQ + vs8 * 8);
        vc1 = *(const bf16x8*)(Vb + (size_t)(vd0 + 32) * SEQ + vs8 * 8);
    }
    *(bf16x8*)&Ks[srow][su * 8] = kst0;
    *(bf16x8*)&Ks[srow + 32][su * 8] = kst1;
    #pragma unroll
    for (int it = 0; it < 4; ++it)
        *(bf16x8*)&Es[srow + 32 * it][su * 8] = est[it];
    __syncthreads();

    for (int r0 = 0; r0 < SEQ; r0 += 64) {
        const int buf = (r0 >> 6) & 1;
        int r0n = r0 + 64; if (r0n >= SEQ) r0n = 0;

        // ---- loop top: mask(t) + coalesced staging loads for t+1 ----
        float4 mk[4];
        #pragma unroll
        for (int q = 0; q < 4; ++q)
            mk[q] = *(const float4*)(mrow_base + r0 + c0q + 4 * q);
        bf16x8 vn0, vn1;
        {
            const int jbn = l0 - r0n + 960;
            kst0 = *(const bf16x8*)(Kb + (size_t)(r0n + srow) * HD + sswz);
            kst1 = *(const bf16x8*)(Kb + (size_t)(r0n + srow + 32) * HD + sswz);
            #pragma unroll
            for (int it = 0; it < 4; ++it)
                est[it] = *(const bf16x8*)(Eg + (size_t)(jbn + srow + 32 * it) * HD + sswz);
            vn0 = *(const bf16x8*)(Vb + (size_t)vd0 * SEQ + r0n + vs8 * 8);
            vn1 = *(const bf16x8*)(Vb + (size_t)(vd0 + 32) * SEQ + r0n + vs8 * 8);
        }

        // ---- cluster 1: S1 (kb frags from Ks LDS) ----
        {
            f32x16 s1a;
            #pragma unroll
            for (int r = 0; r < 16; ++r) s1a[r] = 0.f;
            __builtin_amdgcn_s_setprio(1);
            #pragma unroll
            for (int kc = 0; kc < 4; ++kc) {
                bf16x8 kbv = *(const bf16x8*)&Ks[CB + c][((kc * 2 + h2) ^ swk) * 8];
                s1a = __builtin_amdgcn_mfma_f32_32x32x16_bf16(qa[kc], kbv, s1a, 0, 0, 0);
            }
            __builtin_amdgcn_s_setprio(0);
            #pragma unroll
            for (int rq = 0; rq < 16; ++rq)
                S1[RB + ROWFN(rq, h2)][CB + c] = s1a[rq];
        }
        __builtin_amdgcn_sched_barrier(0);

        // ---- cluster 2: M0/N0 (e0/ka frags from LDS); wave2 skips ma0, wave0 skips na0 ----
        {
            f32x16 ma0, na0;
            #pragma unroll
            for (int r = 0; r < 16; ++r) { ma0[r] = 0.f; na0[r] = 0.f; }
            __builtin_amdgcn_s_setprio(1);
            #pragma unroll
            for (int kc = 0; kc < 4; ++kc) {
                bf16x8 e0v = *(const bf16x8*)&Es[j0][((kc * 2 + h2) ^ swk) * 8];
                if (wid != 2)
                    ma0 = __builtin_amdgcn_mfma_f32_32x32x16_bf16(qa[kc], e0v, ma0, 0, 0, 0);
                if (wid != 0) {
                    bf16x8 kav = *(const bf16x8*)&Ks[RB + c][((kc * 2 + h2) ^ swk) * 8];
                    na0 = __builtin_amdgcn_mfma_f32_32x32x16_bf16(kav, e0v, na0, 0, 0, 0);
                }
            }
            __builtin_amdgcn_s_setprio(0);
            if (wid != 2) {
                #pragma unroll
                for (int q8 = 0; q8 < 8; ++q8) {
                    const unsigned w = cvtpk(ma0[2 * q8], ma0[2 * q8 + 1]);
                    const int lr = RB + ROWFN(2 * q8, h2);   // ROWFN(2q+1)=ROWFN(2q)+1
                    const int rA = lr - j0 + 63;
                    if ((unsigned)rA < 64u) MSS[lr][rA] = (unsigned short)w;
                    if ((unsigned)(rA + 1) < 64u) MSS[lr + 1][rA + 1] = (unsigned short)(w >> 16);
                }
            }
            if (wid != 0) {
                #pragma unroll
                for (int q8 = 0; q8 < 8; ++q8) {
                    const unsigned w = cvtpk(na0[2 * q8], na0[2 * q8 + 1]);
                    const int lr = RB + ROWFN(2 * q8, h2);
                    const int lA = j0 + lr - 63;
                    if ((unsigned)lA < 64u) NST[lA][lr] = (unsigned short)w;
                    if ((unsigned)(lA + 1) < 64u) NST[lA + 1][lr + 1] = (unsigned short)(w >> 16);
                }
            }
        }
        __builtin_amdgcn_sched_barrier(0);

        // ---- cluster 3: M1/N1 (e1 frags from LDS); wave1 skips ma1, wave3 skips na1 ----
        {
            f32x16 ma1, na1;
            #pragma unroll
            for (int r = 0; r < 16; ++r) { ma1[r] = 0.f; na1[r] = 0.f; }
            __builtin_amdgcn_s_setprio(1);
            #pragma unroll
            for (int kc = 0; kc < 4; ++kc) {
                bf16x8 e1v = *(const bf16x8*)&Es[j0 + 32][((kc * 2 + h2) ^ swk) * 8];
                if (wid != 1)
                    ma1 = __builtin_amdgcn_mfma_f32_32x32x16_bf16(qa[kc], e1v, ma1, 0, 0, 0);
                if (wid != 3) {
                    bf16x8 kav = *(const bf16x8*)&Ks[RB + c][((kc * 2 + h2) ^ swk) * 8];
                    na1 = __builtin_amdgcn_mfma_f32_32x32x16_bf16(kav, e1v, na1, 0, 0, 0);
                }
            }
            __builtin_amdgcn_s_setprio(0);
            if (wid != 1) {
                #pragma unroll
                for (int q8 = 0; q8 < 8; ++q8) {
                    const unsigned w = cvtpk(ma1[2 * q8], ma1[2 * q8 + 1]);
                    const int lr = RB + ROWFN(2 * q8, h2);
                    const int rB = lr - j0 + 31;
                    if ((unsigned)rB < 64u) MSS[lr][rB] = (unsigned short)w;
                    if ((unsigned)(rB + 1) < 64u) MSS[lr + 1][rB + 1] = (unsigned short)(w >> 16);
                }
            }
            if (wid != 3) {
                #pragma unroll
                for (int q8 = 0; q8 < 8; ++q8) {
                    const unsigned w = cvtpk(na1[2 * q8], na1[2 * q8 + 1]);
                    const int lr = RB + ROWFN(2 * q8, h2);
                    const int lB = j0 + lr - 31;
                    if ((unsigned)lB < 64u) NST[lB][lr] = (unsigned short)w;
                    if ((unsigned)(lB + 1) < 64u) NST[lB + 1][lr + 1] = (unsigned short)(w >> 16);
                }
            }
        }
        __builtin_amdgcn_sched_barrier(0);

        LBAR();            // BARRIER-A: S1/MSS/NST visible; all Ks/Es/Vt reads(t) done

        // ---- stage Vt(t) + Ks/Es(t+1) from regs (visible after BARRIER-B) ----
        *(bf16x8*)&Vt[vd0][(vs8 ^ kd0) * 8] = vc0;
        *(bf16x8*)&Vt[vd0 + 32][(vs8 ^ kd1) * 8] = vc1;
        *(bf16x8*)&Ks[srow][su * 8] = kst0;
        *(bf16x8*)&Ks[srow + 32][su * 8] = kst1;
        #pragma unroll
        for (int it = 0; it < 4; ++it)
            *(bf16x8*)&Es[srow + 32 * it][su * 8] = est[it];

        // ---- softmax: thread owns row li, cols c0q..c0q+15 (all-vector reads) ----
        float4 s4[4]; ushort4 mm[4], nn[4];
        #pragma unroll
        for (int q = 0; q < 4; ++q) {
            s4[q] = *(const float4*)&S1[li][c0q + 4 * q];
            mm[q] = *(const ushort4*)&MSS[li][c0q + 4 * q];
            nn[q] = *(const ushort4*)&NST[li][c0q + 4 * q];
        }
        float sc[16];
        #pragma unroll
        for (int j = 0; j < 16; ++j) {
            float mv = b2f(u16g(mm[j >> 2], j & 3));
            float nv = b2f(u16g(nn[j >> 2], j & 3));
            sc[j] = (g4(s4[j >> 2], j & 3) + mv + nv) * SC2 + g4(mk[j >> 2], j & 3) * LOG2E;
        }
        float tmax = sc[0];
        #pragma unroll
        for (int j = 1; j < 16; ++j) tmax = fmaxf(tmax, sc[j]);
        tmax = fmaxf(tmax, __shfl_xor(tmax, 1));
        tmax = fmaxf(tmax, __shfl_xor(tmax, 2));
        const bool upd = tmax > m_run + DTHR;          // defer-max (T13)
        const float m_new = upd ? tmax : m_run;
        const float corr = upd ? __builtin_amdgcn_exp2f(m_run - m_new) : 1.0f;
        if (upd) Fl[buf] = 1;                          // benign same-value race
        float tsum = 0.f;
        unsigned pw[8];
        #pragma unroll
        for (int j = 0; j < 8; ++j) {
            float p0 = __builtin_amdgcn_exp2f(sc[2 * j] - m_new);
            float p1 = __builtin_amdgcn_exp2f(sc[2 * j + 1] - m_new);
            tsum += p0;
            tsum += p1;
            pw[j] = cvtpk(p0, p1);                     // [p1:p0] = bf16x8 word order
        }
        tsum += __shfl_xor(tsum, 1);
        tsum += __shfl_xor(tsum, 2);
        lsum = lsum * corr + tsum;
        m_run = m_new;
        if ((tid & 3) == 0) Corr[li] = corr;
        #pragma unroll
        for (int sblk = 0; sblk < 2; ++sblk) {
            union { unsigned u[4]; bf16x8 v; } pk;
            pk.u[0] = pw[sblk * 4 + 0];
            pk.u[1] = pw[sblk * 4 + 1];
            pk.u[2] = pw[sblk * 4 + 2];
            pk.u[3] = pw[sblk * 4 + 3];
            const int slot = ((c0q >> 3) + sblk) ^ kli;
            *(bf16x8*)&Pl[li][slot * 8] = pk.v;
        }

        LBAR();            // BARRIER-B: Pl/Corr/Fl + Vt/Ks/Es writes visible

        // ---- PV ----
        if (Fl[buf]) {
            #pragma unroll
            for (int q = 0; q < 4; ++q) {
                float4 cr = *(const float4*)&Corr[RB + 8 * q + 4 * h2];
                Oa[4 * q + 0] *= cr.x; Oa[4 * q + 1] *= cr.y;
                Oa[4 * q + 2] *= cr.z; Oa[4 * q + 3] *= cr.w;
            }
        }
        if (tid == 0) Fl[buf ^ 1] = 0;
        const int lrow = RB + c;
        const int drow = CB + c;
        const int klr = (lrow ^ (lrow >> 3)) & 7;
        const int kdr = (drow ^ (drow >> 3)) & 7;
        __builtin_amdgcn_s_setprio(1);
        #pragma unroll
        for (int kc = 0; kc < 4; ++kc) {
            const int slot = kc * 2 + h2;
            bf16x8 pa  = *(const bf16x8*)&Pl[lrow][(slot ^ klr) * 8];
            bf16x8 vbf = *(const bf16x8*)&Vt[drow][(slot ^ kdr) * 8];
            Oa = __builtin_amdgcn_mfma_f32_32x32x16_bf16(pa, vbf, Oa, 0, 0, 0);
        }
        __builtin_amdgcn_s_setprio(0);

        vc0 = vn0; vc1 = vn1;
    }

    if ((tid & 3) == 0) InvL[li] = 1.0f / lsum;
    __syncthreads();
    #pragma unroll
    for (int q = 0; q < 4; ++q) {
        float4 iv = *(const float4*)&InvL[RB + 8 * q + 4 * h2];
        #pragma unroll
        for (int e = 0; e < 4; ++e) {
            const int l = RB + 8 * q + 4 * h2 + e;
            out[((size_t)b * SEQ + l0 + l) * HID + hh * HD + CB + c] = Oa[4 * q + e] * g4(iv, e);
        }
    }
}

// ------------------------------------------------------------------
extern "C" void kernel_launch(void* const* d_in, const int* in_sizes, int n_in,
                              void* d_out, int out_size, void* d_ws, size_t ws_size,
                              hipStream_t stream) {
    const float* hidden = (const float*)d_in[0];
    const float* mask   = (const float*)d_in[1];
    const float* Wq     = (const float*)d_in[2];
    const float* bq     = (const float*)d_in[3];
    const float* Wk     = (const float*)d_in[4];
    const float* bk     = (const float*)d_in[5];
    const float* Wv     = (const float*)d_in[6];
    const float* bv     = (const float*)d_in[7];
    const float* E      = (const float*)d_in[8];
    float* outp = (float*)d_out;

    unsigned short* ws  = (unsigned short*)d_ws;
    unsigned short* Xbf = ws;                      // 4096*768            = 3145728
    unsigned short* Wt  = ws + 3145728;            // 3*768*768           = 1769472
    unsigned short* Ebf = ws + 4915200;            // 2047*64             = 131008
    unsigned short* qkv = ws + 5046272;            // 3*48*1024*64        = 9437184

    prep<<<dim3(NWT + NCVT), 256, 0, stream>>>(hidden, E, Wq, Wk, Wv, Xbf, Ebf, Wt);
    gemm_qkv<<<dim3(32, 6, 3), 256, 0, stream>>>(Xbf, Wt, bq, bk, bv, qkv);
    const size_t per = (size_t)NB * SEQ * HID;
    attn_mfma<<<dim3(16, 48), 256, 0, stream>>>(qkv, qkv + per, qkv + 2 * per,
                                                Ebf, mask, outp);
}